// Round 7
// baseline (2508.814 us; speedup 1.0000x reference)
//
#include <hip/hip_runtime.h>
#include <math.h>

// GCN 2-layer, f32 in/out. N=100000, E=3200000, F_in=512, H=16, C=7.
// Round 13: persistent-kernel retry. R12 deadlocked: no min-occupancy bound ->
// compiler free to blow past 170 VGPR -> only 2 blocks/CU resident while the
// barrier waited for 3/CU (768). Fix: NB=512 (2 blocks/CU) and
// __launch_bounds__(256,2) which GUARANTEES 2 blocks/CU schedulability
// (VGPR<=256/wave, LDS 66KB/CU < 160KB). Phase bodies identical to R10
// (best dispatch-based: 448.5us); two-level device-scope barrier between
// phases; k_init zeroes barrier state + csr pad each replay.

#define F_IN 512
#define HID  16
#define NCLS 7
#define NCHUNK 256
#define BK 256        // nodes per bucket
#define NBMAX 400     // >= nb = ceil(N/256) = 391
#define WT_STRIDE 516 // padded k-stride of transposed W1 in LDS
#define NB 512        // persistent grid (2 blocks/CU guaranteed resident)
#define SMB (HID * WT_STRIDE * 4)  // 33024 B shared union

static __device__ __forceinline__ unsigned short f2bf(float f) {
    union { float f; unsigned int u; } v; v.f = f;
    unsigned int b = v.u;
    return (unsigned short)((b + 0x7FFFu + ((b >> 16) & 1u)) >> 16);  // RNE
}

// ---- device-scope grid barrier (single-use per slot) ----
// slot layout: [0] release flag, [32..63] arrival counters (32-way split)
static __device__ void gsync(int* bar, int slot) {
    __syncthreads();
    if (threadIdx.x == 0) {
        int* base = bar + slot * 64;
        __threadfence();
        __hip_atomic_fetch_add(&base[32 + (blockIdx.x & 31)], 1,
                               __ATOMIC_RELEASE, __HIP_MEMORY_SCOPE_AGENT);
        if (blockIdx.x == 0) {
            int s;
            do {
                __builtin_amdgcn_s_sleep(2);
                s = 0;
#pragma unroll
                for (int c = 0; c < 32; ++c)
                    s += __hip_atomic_load(&base[32 + c], __ATOMIC_ACQUIRE,
                                           __HIP_MEMORY_SCOPE_AGENT);
            } while (s < NB);
            __hip_atomic_store(&base[0], 1, __ATOMIC_RELEASE,
                               __HIP_MEMORY_SCOPE_AGENT);
        } else {
            while (!__hip_atomic_load(&base[0], __ATOMIC_ACQUIRE,
                                      __HIP_MEMORY_SCOPE_AGENT))
                __builtin_amdgcn_s_sleep(2);
        }
        __threadfence();
    }
    __syncthreads();
}

// ---- init: zero barrier state + csr pad (re-run every iteration) ----
__global__ void k_init(int* bar, int* csr, int E) {
    int t = threadIdx.x;
    for (int i = t; i < 8 * 64; i += 256) bar[i] = 0;
    if (t < 16) csr[E + t] = 0;
}

// ================= phase bodies (R10 semantics) =================

static __device__ void a1_body(int c, const int* __restrict__ ei, int E, int perChunk,
                               int nb, int* __restrict__ bh, int* hist) {
    for (int t = threadIdx.x; t < nb; t += 256) hist[t] = 0;
    __syncthreads();
    const int* dst = ei + E;
    int s0 = c * perChunk;
    int s1 = min(s0 + perChunk, E);
    for (int e = s0 + threadIdx.x; e < s1; e += 256)
        atomicAdd(&hist[dst[e] >> 8], 1);
    __syncthreads();
    for (int t = threadIdx.x; t < nb; t += 256) bh[(size_t)c * nb + t] = hist[t];
    __syncthreads();
}

static __device__ void a2a_body(int b, int* __restrict__ bh, int nb,
                                int* __restrict__ Tb, int* sd) {
    int tid = threadIdx.x;
    int v = bh[(size_t)tid * nb + b];
    sd[tid] = v;
    __syncthreads();
    for (int off = 1; off < 256; off <<= 1) {
        int t = (tid >= off) ? sd[tid - off] : 0;
        __syncthreads();
        sd[tid] += t;
        __syncthreads();
    }
    bh[(size_t)tid * nb + b] = sd[tid] - v;
    if (tid == 255) Tb[b] = sd[255];
    __syncthreads();
}

static __device__ void a2b_body(const int* __restrict__ Tb, int nb,
                                int* __restrict__ Bb, int* sd) {
    int tid = threadIdx.x;
    int carry = 0;
    for (int base = 0; base < nb; base += 256) {
        int v = (base + tid < nb) ? Tb[base + tid] : 0;
        sd[tid] = v;
        __syncthreads();
        for (int off = 1; off < 256; off <<= 1) {
            int t = (tid >= off) ? sd[tid - off] : 0;
            __syncthreads();
            sd[tid] += t;
            __syncthreads();
        }
        if (base + tid < nb) Bb[base + tid] = carry + sd[tid] - v;
        carry += sd[255];
        __syncthreads();
    }
}

static __device__ void a3_body(int c, const int* __restrict__ ei, int E, int perChunk,
                               int nb, const int* __restrict__ bh,
                               const int* __restrict__ Bb,
                               unsigned* __restrict__ part,
                               int* cur, int* baseL) {
    for (int t = threadIdx.x; t < nb; t += 256) {
        cur[t] = 0;
        baseL[t] = Bb[t] + bh[(size_t)c * nb + t];
    }
    __syncthreads();
    const int* src = ei;
    const int* dst = ei + E;
    int s0 = c * perChunk;
    int s1 = min(s0 + perChunk, E);
    for (int e = s0 + threadIdx.x; e < s1; e += 256) {
        int s = src[e], d = dst[e];
        int b = d >> 8;
        int r = atomicAdd(&cur[b], 1);
        part[baseL[b] + r] = ((unsigned)(d & (BK - 1)) << 20) | (unsigned)s;
    }
    __syncthreads();
}

// counting sort without LDS edge staging (re-reads L2-warm bucket)
static __device__ void kb_body(int b, const unsigned* __restrict__ part,
                               const int* __restrict__ Tb,
                               const int* __restrict__ Bb,
                               int* __restrict__ csr, int* __restrict__ cnt,
                               int* __restrict__ offs, float* __restrict__ dinv,
                               int N, int* hist, int* sd, int* cur) {
    int tid = threadIdx.x;
    int base = Bb[b], ct = Tb[b];
    hist[tid] = 0;
    __syncthreads();
    for (int k = tid; k < ct; k += 256)
        atomicAdd(&hist[part[base + k] >> 20], 1);
    __syncthreads();
    sd[tid] = hist[tid];
    __syncthreads();
    for (int off = 1; off < BK; off <<= 1) {
        int t = (tid >= off) ? sd[tid - off] : 0;
        __syncthreads();
        sd[tid] += t;
        __syncthreads();
    }
    {
        int h = hist[tid];
        int ex = sd[tid] - h;
        cur[tid] = ex;
        int node = b * BK + tid;
        if (node < N) {
            cnt[node] = h;
            offs[node] = base + ex;
            dinv[node] = rsqrtf((float)h + 1.0f);
        }
    }
    __syncthreads();
    for (int k = tid; k < ct; k += 256) {
        unsigned v = part[base + k];
        int dl = (int)(v >> 20);
        int r = atomicAdd(&cur[dl], 1);
        csr[base + r] = (int)(v & 0xFFFFFu);
    }
    __syncthreads();
}

// gemm unit: reads pre-staged wlT only (no LDS writes, no syncthreads)
static __device__ void gemm_unit(int gb, const float* __restrict__ x,
                                 const float* __restrict__ dinv,
                                 unsigned short* __restrict__ hs1b, int N,
                                 const float* wlT) {
    int lane = threadIdx.x & 15;
    int g = threadIdx.x >> 4;
    int rbase = gb * 64 + g * 4;

    const float* xp0 = x + (size_t)(rbase + 0 < N ? rbase + 0 : 0) * F_IN + 4 * lane;
    const float* xp1 = x + (size_t)(rbase + 1 < N ? rbase + 1 : 0) * F_IN + 4 * lane;
    const float* xp2 = x + (size_t)(rbase + 2 < N ? rbase + 2 : 0) * F_IN + 4 * lane;
    const float* xp3 = x + (size_t)(rbase + 3 < N ? rbase + 3 : 0) * F_IN + 4 * lane;

    float4 a0 = *(const float4*)(xp0);
    float4 a1 = *(const float4*)(xp1);
    float4 a2 = *(const float4*)(xp2);
    float4 a3 = *(const float4*)(xp3);

    float acc[4][16];
#pragma unroll
    for (int r = 0; r < 4; ++r)
#pragma unroll
        for (int j = 0; j < 16; ++j) acc[r][j] = 0.0f;

    auto fma_block = [&](int p, const float4& A0, const float4& A1,
                         const float4& A2, const float4& A3) {
        const float* wb = &wlT[64 * p + 4 * lane];
#pragma unroll
        for (int j = 0; j < 16; ++j) {
            float4 w4 = *(const float4*)(wb + (size_t)j * WT_STRIDE);
            acc[0][j] = fmaf(A0.x, w4.x, fmaf(A0.y, w4.y, fmaf(A0.z, w4.z, fmaf(A0.w, w4.w, acc[0][j]))));
            acc[1][j] = fmaf(A1.x, w4.x, fmaf(A1.y, w4.y, fmaf(A1.z, w4.z, fmaf(A1.w, w4.w, acc[1][j]))));
            acc[2][j] = fmaf(A2.x, w4.x, fmaf(A2.y, w4.y, fmaf(A2.z, w4.z, fmaf(A2.w, w4.w, acc[2][j]))));
            acc[3][j] = fmaf(A3.x, w4.x, fmaf(A3.y, w4.y, fmaf(A3.z, w4.z, fmaf(A3.w, w4.w, acc[3][j]))));
        }
    };

#pragma unroll 1
    for (int p = 0; p < 7; ++p) {
        float4 n0 = *(const float4*)(xp0 + 64 * (p + 1));
        float4 n1 = *(const float4*)(xp1 + 64 * (p + 1));
        float4 n2 = *(const float4*)(xp2 + 64 * (p + 1));
        float4 n3 = *(const float4*)(xp3 + 64 * (p + 1));
        fma_block(p, a0, a1, a2, a3);
        a0 = n0; a1 = n1; a2 = n2; a3 = n3;
    }
    fma_block(7, a0, a1, a2, a3);

    bool b8 = (lane & 8) != 0, b4 = (lane & 4) != 0, b2 = (lane & 2) != 0, b1 = (lane & 1) != 0;
#pragma unroll
    for (int r = 0; r < 4; ++r) {
#pragma unroll
        for (int j = 0; j < 8; ++j) {
            float lo = acc[r][j], hi = acc[r][j + 8];
            float keep = b8 ? hi : lo;
            float send = b8 ? lo : hi;
            acc[r][j] = keep + __shfl_xor(send, 8, 16);
        }
#pragma unroll
        for (int j = 0; j < 4; ++j) {
            float lo = acc[r][j], hi = acc[r][j + 4];
            float keep = b4 ? hi : lo;
            float send = b4 ? lo : hi;
            acc[r][j] = keep + __shfl_xor(send, 4, 16);
        }
#pragma unroll
        for (int j = 0; j < 2; ++j) {
            float lo = acc[r][j], hi = acc[r][j + 2];
            float keep = b2 ? hi : lo;
            float send = b2 ? lo : hi;
            acc[r][j] = keep + __shfl_xor(send, 2, 16);
        }
        {
            float lo = acc[r][0], hi = acc[r][1];
            float keep = b1 ? hi : lo;
            float send = b1 ? lo : hi;
            acc[r][0] = keep + __shfl_xor(send, 1, 16);
        }
        int row = rbase + r;
        if (row < N)
            hs1b[(size_t)row * HID + lane] = f2bf(dinv[row] * acc[r][0]);
    }
}

// ================= persistent kernel =================

__global__ __launch_bounds__(256, 2) void k_persist(
        const int* __restrict__ ei, int E, int perChunk, int nb,
        int* __restrict__ bh, int* __restrict__ Tb, int* __restrict__ Bb,
        unsigned* __restrict__ part, int* __restrict__ csr,
        int* __restrict__ cnt, int* __restrict__ offs, float* __restrict__ dinv,
        const float* __restrict__ x, const float* __restrict__ W1,
        unsigned short* __restrict__ hs1b,
        const float* __restrict__ b1, const float* __restrict__ W2,
        float* __restrict__ hs2p, const float* __restrict__ b2,
        float* __restrict__ out, int N, int* bar) {
    __shared__ __align__(16) unsigned char sm[SMB];
    const int bid = blockIdx.x;

    // ---- phase 0: a1 histograms ----
    for (int u = bid; u < NCHUNK; u += NB)
        a1_body(u, ei, E, perChunk, nb, bh, (int*)sm);
    gsync(bar, 0);

    // ---- phase 1: a2a per-bucket chunk scan ----
    for (int u = bid; u < nb; u += NB)
        a2a_body(u, bh, nb, Tb, (int*)sm);
    gsync(bar, 1);

    // ---- phase 2: a2b bucket-base scan (block 0 only) ----
    if (bid == 0) a2b_body(Tb, nb, Bb, (int*)sm);
    gsync(bar, 2);

    // ---- phase 3: a3 partition scatter ----
    for (int u = bid; u < NCHUNK; u += NB)
        a3_body(u, ei, E, perChunk, nb, bh, Bb, part,
                (int*)sm, (int*)sm + NBMAX);
    gsync(bar, 3);

    // ---- phase 4: k_b counting sort ----
    for (int u = bid; u < nb; u += NB)
        kb_body(u, part, Tb, Bb, csr, cnt, offs, dinv, N,
                (int*)sm, (int*)sm + 256, (int*)sm + 512);
    gsync(bar, 4);

    // ---- phase 5: gemm1 (stage W1^T once, then read-only units) ----
    {
        float* wlT = (float*)sm;
        int j = threadIdx.x & 15;
        int k0 = threadIdx.x >> 4;
        for (int it = 0; it < F_IN / 16; ++it) {
            int k = k0 + 16 * it;
            wlT[j * WT_STRIDE + k] = W1[k * HID + j];
        }
        __syncthreads();
        const int gemmNB = (N + 63) / 64;
        for (int u = bid; u < gemmNB; u += NB)
            gemm_unit(u, x, dinv, hs1b, N, wlT);
    }
    gsync(bar, 5);

    // ---- phase 6: agg1 ----
    {
        const unsigned* hs1u = (const unsigned*)hs1b;
        int lane = threadIdx.x & 7;
        float w2a[NCLS], w2b[NCLS];
#pragma unroll
        for (int c = 0; c < NCLS; c++) {
            w2a[c] = W2[(2 * lane) * NCLS + c];
            w2b[c] = W2[(2 * lane + 1) * NCLS + c];
        }
        float b1a = b1[2 * lane], b1b = b1[2 * lane + 1];
        const int aggNB = (N + 31) / 32;
        for (int u = bid; u < aggNB; u += NB) {
            int i = u * 32 + (threadIdx.x >> 3);
            if (i >= N) continue;  // group-uniform
            int start = offs[i], cn = cnt[i];
            unsigned su = hs1u[(size_t)i * 8 + lane];
            float accA = __uint_as_float(su << 16);
            float accB = __uint_as_float(su & 0xffff0000u);
            int full = cn & ~7;
            int rem = cn - full;
            int evn = csr[start + lane];
            for (int k = 0; k < full; k += 8) {
                int ev = evn;
                evn = csr[start + k + 8 + lane];
#pragma unroll
                for (int t = 0; t < 8; ++t) {
                    int s = __shfl(ev, t, 8);
                    unsigned uu = hs1u[(size_t)s * 8 + lane];
                    accA += __uint_as_float(uu << 16);
                    accB += __uint_as_float(uu & 0xffff0000u);
                }
            }
            for (int t = 0; t < rem; ++t) {
                int s = __shfl(evn, t, 8);
                unsigned uu = hs1u[(size_t)s * 8 + lane];
                accA += __uint_as_float(uu << 16);
                accB += __uint_as_float(uu & 0xffff0000u);
            }
            float dv = dinv[i];
            float vA = fmaf(dv, accA, b1a);
            float vB = fmaf(dv, accB, b1b);
            float hA = vA > 0.0f ? vA : 0.0f;
            float hB = vB > 0.0f ? vB : 0.0f;
            float res[NCLS];
#pragma unroll
            for (int c = 0; c < NCLS; c++) {
                float t = fmaf(hA, w2a[c], hB * w2b[c]);
#pragma unroll
                for (int w = 4; w >= 1; w >>= 1) t += __shfl_xor(t, w, 8);
                res[c] = t;
            }
            float o = res[0];
#pragma unroll
            for (int c = 1; c < NCLS; c++) o = (lane == c) ? res[c] : o;
            hs2p[(size_t)i * 8 + lane] = dv * o;
        }
    }
    gsync(bar, 6);

    // ---- phase 7: agg2 + log_softmax ----
    {
        int lane = threadIdx.x & 7;
        const int aggNB = (N + 31) / 32;
        for (int u = bid; u < aggNB; u += NB) {
            int i = u * 32 + (threadIdx.x >> 3);
            if (i >= N) continue;  // group-uniform
            int start = offs[i], cn = cnt[i];
            float acc = hs2p[(size_t)i * 8 + lane];
            int full = cn & ~7;
            int rem = cn - full;
            int evn = csr[start + lane];
            for (int k = 0; k < full; k += 8) {
                int ev = evn;
                evn = csr[start + k + 8 + lane];
#pragma unroll
                for (int t = 0; t < 8; ++t) {
                    int s = __shfl(ev, t, 8);
                    acc += hs2p[(size_t)s * 8 + lane];
                }
            }
            for (int t = 0; t < rem; ++t) {
                int s = __shfl(evn, t, 8);
                acc += hs2p[(size_t)s * 8 + lane];
            }
            int cc = lane < NCLS ? lane : NCLS - 1;
            float v = fmaf(dinv[i], acc, b2[cc]);
            float vm = (lane < NCLS) ? v : -INFINITY;
            float m = vm;
#pragma unroll
            for (int w = 4; w >= 1; w >>= 1) m = fmaxf(m, __shfl_xor(m, w, 8));
            float e = (lane < NCLS) ? expf(v - m) : 0.0f;
            float ssum = e;
#pragma unroll
            for (int w = 4; w >= 1; w >>= 1) ssum += __shfl_xor(ssum, w, 8);
            if (lane < NCLS) out[(size_t)i * NCLS + lane] = v - m - logf(ssum);
        }
    }
}

extern "C" void kernel_launch(void* const* d_in, const int* in_sizes, int n_in,
                              void* d_out, int out_size, void* d_ws, size_t ws_size,
                              hipStream_t stream) {
    const float* x  = (const float*)d_in[0];
    const int*   ei = (const int*)d_in[1];
    const float* W1 = (const float*)d_in[2];
    const float* b1 = (const float*)d_in[3];
    const float* W2 = (const float*)d_in[4];
    const float* b2 = (const float*)d_in[5];
    float* out = (float*)d_out;

    const int N = in_sizes[0] / F_IN;          // 100000
    const int E = in_sizes[1] / 2;             // 3200000
    const int nb = (N + BK - 1) / BK;          // 391
    const int perChunk = (E + NCHUNK - 1) / NCHUNK;  // 12500

    // ws layout in 4B words, 16B-aligned chunks:
    // [part E | hs2p 8N (aliased)][csr E+16][hs1b 8N(u32)][dinv N][cnt N]
    // [offs N][bh 256*nb][Tb nb][Bb nb][bar 512]
    unsigned* w = (unsigned*)d_ws;
    auto al4 = [](size_t v) { return (v + 3) & ~(size_t)3; };
    size_t o = 0;
    unsigned*       part = w + o;
    float*          hs2p = (float*)(w + o);     o = al4(o + E);
    int*            csr  = (int*)(w + o);       o = al4(o + E + 16);
    unsigned short* hs1b = (unsigned short*)(w + o); o = al4(o + (size_t)N * HID / 2);
    float*          dinv = (float*)(w + o);     o = al4(o + N);
    int*            cnt  = (int*)(w + o);       o = al4(o + N);
    int*            offs = (int*)(w + o);       o = al4(o + N);
    int*            bh   = (int*)(w + o);       o = al4(o + (size_t)NCHUNK * nb);
    int*            Tb   = (int*)(w + o);       o = al4(o + nb);
    int*            Bb   = (int*)(w + o);       o = al4(o + nb);
    int*            bar  = (int*)(w + o);       o = al4(o + 512);

    k_init<<<1, 256, 0, stream>>>(bar, csr, E);
    k_persist<<<NB, 256, 0, stream>>>(ei, E, perChunk, nb, bh, Tb, Bb, part, csr,
                                      cnt, offs, dinv, x, W1, hs1b, b1, W2, hs2p,
                                      b2, out, N, bar);
}